// Round 6
// baseline (3110.810 us; speedup 1.0000x reference)
//
#include <hip/hip_runtime.h>
#include <stdint.h>

// ---------------------------------------------------------------------------
// Fused SDE sampler, round 8: C-INIT BIAS FOLD + BIAS REG HOIST + LDS SWIZZLE.
//   Round-7 lesson: phase interleave neutral -> compiler already extracts
//   region ILP; kernel is VALU-WORK-bound.  This round deletes issue slots:
//   - biases folded into MFMA C-init (L1: pre + s*W1s + b1; L2: b2; L3: b3)
//     -> post-MFMA epilogues reduce to relu+cvt only (-~140 VALU/thread-step)
//   - b1/W1s/b2/b3 hoisted from LDS to 28 VGPRs (loaded once) -> -22
//     ds_read_b128 per wave-step
//   - fragment tiles XOR-swizzled (byte ^= bit7<<... -> bit5): producer f16x4
//     writes go 4-way -> 2-way banks (free), reads stay conflict-free
//   - sqrt(2) folded into erfinv coefficients (round-7 verified variant)
//   Structure = round 6 (best measured): L1 | L2+nextRNG | L3+update,
//   weights in 112 VGPRs, x0-hoist, fragment-linear LDS, bit-exact threefry.
// ---------------------------------------------------------------------------

#define PARTITIONABLE 1

namespace {

constexpr int   kObs    = 65536;
constexpr int   kDim    = 64;
constexpr int   kSteps  = 64;
constexpr float kDs     = 1.0f / 64.0f;
constexpr float kSqrtDs = 0.125f;

constexpr int kWeightBytes = 256 * 1024;          // 8 waves x 32 tiles x 1 KB
constexpr int kKeysOff     = kWeightBytes;        // uint32[2][64][2] = 1 KB
constexpr int kStabOff     = kKeysOff + 1024;     // f32x4[64]        = 1 KB

typedef _Float16 f16x8 __attribute__((ext_vector_type(8)));
typedef _Float16 f16x4 __attribute__((ext_vector_type(4)));
typedef float    f32x4 __attribute__((ext_vector_type(4)));

#define MFMA16(a, b, c) __builtin_amdgcn_mfma_f32_16x16x32_f16((a), (b), (c), 0, 0, 0)
// XOR-swizzle a byte-offset within a 1 KB fragment tile: bit5 ^= bit7.
#define SWZ(b) ((b) ^ (((b) >> 2) & 0x20))

__device__ __forceinline__ uint32_t rotl(uint32_t v, int r) {
  return (v << r) | (v >> (32 - r));
}

__device__ __forceinline__ void tf2x32(uint32_t k0, uint32_t k1,
                                       uint32_t& x0, uint32_t& x1) {
  uint32_t k2 = k0 ^ k1 ^ 0x1BD11BDAu;
  x0 += k0; x1 += k1;
  x0 += x1; x1 = rotl(x1, 13); x1 ^= x0;
  x0 += x1; x1 = rotl(x1, 15); x1 ^= x0;
  x0 += x1; x1 = rotl(x1, 26); x1 ^= x0;
  x0 += x1; x1 = rotl(x1,  6); x1 ^= x0;
  x0 += k1; x1 += k2 + 1u;
  x0 += x1; x1 = rotl(x1, 17); x1 ^= x0;
  x0 += x1; x1 = rotl(x1, 29); x1 ^= x0;
  x0 += x1; x1 = rotl(x1, 16); x1 ^= x0;
  x0 += x1; x1 = rotl(x1, 24); x1 ^= x0;
  x0 += k2; x1 += k0 + 2u;
  x0 += x1; x1 = rotl(x1, 13); x1 ^= x0;
  x0 += x1; x1 = rotl(x1, 15); x1 ^= x0;
  x0 += x1; x1 = rotl(x1, 26); x1 ^= x0;
  x0 += x1; x1 = rotl(x1,  6); x1 ^= x0;
  x0 += k0; x1 += k1 + 3u;
  x0 += x1; x1 = rotl(x1, 17); x1 ^= x0;
  x0 += x1; x1 = rotl(x1, 29); x1 ^= x0;
  x0 += x1; x1 = rotl(x1, 16); x1 ^= x0;
  x0 += x1; x1 = rotl(x1, 24); x1 ^= x0;
  x0 += k1; x1 += k2 + 4u;
  x0 += x1; x1 = rotl(x1, 13); x1 ^= x0;
  x0 += x1; x1 = rotl(x1, 15); x1 ^= x0;
  x0 += x1; x1 = rotl(x1, 26); x1 ^= x0;
  x0 += x1; x1 = rotl(x1,  6); x1 ^= x0;
  x0 += k2; x1 += k0 + 5u;
}

__device__ __forceinline__ void jax_split(uint32_t k0, uint32_t k1,
                                          uint32_t& a0, uint32_t& a1,
                                          uint32_t& b0, uint32_t& b1) {
#if PARTITIONABLE
  uint32_t x0 = 0u, x1 = 0u; tf2x32(k0, k1, x0, x1); a0 = x0; a1 = x1;
  uint32_t y0 = 0u, y1 = 1u; tf2x32(k0, k1, y0, y1); b0 = y0; b1 = y1;
#else
  uint32_t x0 = 0u, x1 = 2u; tf2x32(k0, k1, x0, x1);
  uint32_t y0 = 1u, y1 = 3u; tf2x32(k0, k1, y0, y1);
  a0 = x0; a1 = y0; b0 = x1; b1 = y1;
#endif
}

__device__ __forceinline__ uint32_t draw_bits(uint32_t k0, uint32_t k1, uint32_t i) {
#if PARTITIONABLE
  uint32_t x0 = 0u, x1 = i;
  tf2x32(k0, k1, x0, x1);
  return x0 ^ x1;
#else
  const uint32_t half = (uint32_t)kObs * kDim / 2;
  if (i < half) {
    uint32_t x0 = i, x1 = i + half; tf2x32(k0, k1, x0, x1); return x0;
  } else {
    uint32_t x0 = i - half, x1 = i; tf2x32(k0, k1, x0, x1); return x1;
  }
#endif
}

// returns sqrt(2)*erfinv(x): sqrt(2) folded into the polynomial coefficients
__device__ __forceinline__ float erfinv32s(float x) {
  float w = -__logf(fmaf(-x, x, 1.0f));
  float p;
  if (w < 5.0f) {
    w = w - 2.5f;
    p =            3.974239e-08f;
    p = fmaf(p, w, 4.854653e-07f);
    p = fmaf(p, w, -4.982823e-06f);
    p = fmaf(p, w, -6.210533e-06f);
    p = fmaf(p, w, 3.091202e-04f);
    p = fmaf(p, w, -1.773035e-03f);
    p = fmaf(p, w, -5.908134e-03f);
    p = fmaf(p, w, 3.488027e-01f);
    p = fmaf(p, w, 2.1233135f);
  } else {
    w = sqrtf(w) - 3.0f;
    p =            -2.8314694e-04f;
    p = fmaf(p, w, 1.4276561e-04f);
    p = fmaf(p, w, 1.908261e-03f);
    p = fmaf(p, w, -5.1950111e-03f);
    p = fmaf(p, w, 8.1168903e-03f);
    p = fmaf(p, w, -1.07797888e-02f);
    p = fmaf(p, w, 1.33485780e-02f);
    p = fmaf(p, w, 1.4165811f);
    p = fmaf(p, w, 4.0064343f);
  }
  return p * x;
}

__device__ __forceinline__ float bits_to_normal(uint32_t bits) {
  const float lo = -0.99999994f;
  float f = __uint_as_float(0x3f800000u | (bits >> 9)) - 1.0f;
  float u = fmaxf(lo, fmaf(f, 2.0f, lo));
  return erfinv32s(u);
}

}  // namespace

// ---------------------------------------------------------------------------
// Weight prep: per-wave contiguous fragment tiles + RNG/step tables.
// (identical to rounds 4-7 — verified)
// ---------------------------------------------------------------------------
__global__ void prep_weights(const float* __restrict__ W1,
                             const float* __restrict__ W2,
                             const float* __restrict__ W3,
                             _Float16* __restrict__ ws) {
  const int G = blockIdx.x;
  const int t = threadIdx.x;

  if (G >= 256) {
    if (t < 2) {
      uint32_t* kout = (uint32_t*)((char*)ws + kKeysOff) + t * 128;
      uint32_t s0a, s0b, s1a, s1b;
      jax_split(0u, 1u, s0a, s0b, s1a, s1b);
      const uint32_t sk0 = t ? s1a : s0a;
      const uint32_t sk1 = t ? s1b : s0b;
      uint32_t kd0, kd1, kl0, kl1;
      jax_split(sk0, sk1, kd0, kd1, kl0, kl1);
      kout[0] = kd0; kout[1] = kd1;
      for (int n = 1; n < kSteps; ++n) {
        uint32_t na, nb, xa, xb;
        jax_split(kl0, kl1, na, nb, xa, xb);
        kl0 = na; kl1 = nb;
        kout[2 * n] = xa; kout[2 * n + 1] = xb;
      }
    }
    if (t < kSteps) {
      const float s  = (float)t * kDs;
      const float sg = 1.0f - s;
      f32x4 v;
      v[0] = s;
      v[1] = (t == 0) ? 0.0f : 1.0f / (s * sg);
      v[2] = 0.5f * (1.0f - sg * sg);
      v[3] = kDs * v[2] * v[1];                    // P = ds*coef*A
      *(f32x4*)((char*)ws + kStabOff + t * 16) = v;
    }
    return;
  }

  const int lane = t >> 2;
  const int j0   = (t & 3) * 2;
  const int w    = G >> 5;
  const int T    = G & 31;
  const int lm   = lane & 15;
  const int kb   = (lane >> 4) << 3;

#pragma unroll
  for (int jj = 0; jj < 2; ++jj) {
    const int j = j0 + jj;
    float v;
    if (T < 8) {
      const int mt = T >> 2, kt = T & 3;
      const int col = w * 32 + mt * 16 + lm;
      const int k   = kt * 32 + kb + j;          // 0..127 : [x | x0] rows of W1
      v = W1[k * 256 + col];
    } else if (T < 24) {
      const int u = T - 8;
      const int mt = u >> 3, kt = u & 7;
      const int col = w * 32 + mt * 16 + lm;
      const int k   = kt * 32 + kb + j;
      v = W2[k * 256 + col];
    } else {
      const int kt  = T - 24;
      const int col = (w >> 1) * 16 + lm;        // L3 dim-tile = w>>1
      const int k   = kt * 32 + kb + j;
      v = W3[k * 64 + col];
    }
    ws[(size_t)G * 512 + lane * 8 + j] = (_Float16)v;
  }
}

// ---------------------------------------------------------------------------
// Main fused kernel.
// ---------------------------------------------------------------------------
__global__ __launch_bounds__(512, 2)
void sde_mfma(const float* __restrict__ X0g,
              const float* __restrict__ W1,
              const float* __restrict__ b1,
              const float* __restrict__ b2,
              const float* __restrict__ b3,
              const _Float16* __restrict__ ws,
              float* __restrict__ out) {
  // Fragment-tile LDS, XOR-swizzled (SWZ) within each 1 KB tile.
  __shared__ alignas(16) char  xAf [8 * 1024];
  __shared__ alignas(16) char  h1f [32 * 1024];   // x0-scratch during init
  __shared__ alignas(16) char  h2f [32 * 1024];
  __shared__ alignas(16) float bb  [832];         // b1|W1s|b2 (256 ea) | b3(64)

  const int t    = threadIdx.x;
  const int w    = t >> 6;                 // wave 0..7: neurons [32w,32w+32)
  const int l    = t & 63;
  const int lq   = l >> 4;
  const int lm   = l & 15;
  const int samp = blockIdx.x >> 10;       // 1024 blocks per sample
  const int tile = blockIdx.x & 1023;
  const int r0   = tile * 64;
  const int mt3  = w >> 1;                 // L3 dim-tile
  const int ntb  = (w & 1) * 2;            // L3 row-tile base (2 tiles)
  const int d0   = mt3 * 16 + lq * 4;      // this lane's 4 dims

  const int rbs  = SWZ(l * 16);                                // consumer read
  const int lo1  = ((lq >> 1) * 16 + lm) * 16 + (lq & 1) * 8;  // producer
  const int lo1s = SWZ(lo1);
  const int kt3  = mt3 >> 1;
  const int ln3  = (((mt3 & 1) * 2 + (lq >> 1)) * 16 + lm) * 16 + (lq & 1) * 8;
  const int ln3s = SWZ(ln3);

  // ---- stage biases + s-row of W1 ----
  if (t < 256) {
    bb[t]       = b1[t];
    bb[256 + t] = W1[128 * 256 + t];
    bb[512 + t] = b2[t];
  } else if (t < 320) {
    bb[768 + (t - 256)] = b3[t - 256];
  }

  // ---- stage X0 into fragment layout: xAf (live) + h1f (hoist scratch) ----
  {
    const int li = t >> 3;                 // row 0..63
    const int ci = (t & 7) * 8;            // dim base
    const float* p = X0g + (size_t)(r0 + li) * kDim + ci;
    const float4 a = *(const float4*)p;
    const float4 b = *(const float4*)(p + 4);
    f16x8 h;
    h[0] = (_Float16)a.x; h[1] = (_Float16)a.y;
    h[2] = (_Float16)a.z; h[3] = (_Float16)a.w;
    h[4] = (_Float16)b.x; h[5] = (_Float16)b.y;
    h[6] = (_Float16)b.z; h[7] = (_Float16)b.w;
    const int fat = ((ci >> 5) * 4 + (li >> 4)) * 1024;
    const int fai = ((((ci >> 3) & 3) * 16 + (li & 15))) * 16;
    *(f16x8*)(xAf + fat + SWZ(fai)) = h;
    *(f16x8*)(h1f + fat + SWZ(fai)) = h;
  }

  // ---- own state: rows (ntb+ni)*16+lm, dims d0..d0+3 ----
  float xv[2][4];
  f32x4 x0q[2];
#pragma unroll
  for (int ni = 0; ni < 2; ++ni) {
    const int row = (ntb + ni) * 16 + lm;
    x0q[ni] = *(const f32x4*)(X0g + (size_t)(r0 + row) * kDim + d0);
#pragma unroll
    for (int q = 0; q < 4; ++q) xv[ni][q] = x0q[ni][q];
  }
  const uint32_t giA = (uint32_t)((r0 + ntb * 16 + lm) * kDim + d0);
  const uint32_t giB = giA + 16u * kDim;

  // ---- preload weight fragments (112 regs) + transient x0-part ----
  const char* pW = (const char*)ws + (size_t)w * 32768 + l * 16;
  f16x8 wL1[2][2], wx0[2][2], wL2[16], wL3[8];
#pragma unroll
  for (int mt = 0; mt < 2; ++mt) {
    wL1[mt][0] = *(const f16x8*)(pW + (mt * 4 + 0) * 1024);
    wL1[mt][1] = *(const f16x8*)(pW + (mt * 4 + 1) * 1024);
    wx0[mt][0] = *(const f16x8*)(pW + (mt * 4 + 2) * 1024);
    wx0[mt][1] = *(const f16x8*)(pW + (mt * 4 + 3) * 1024);
  }
#pragma unroll
  for (int i = 0; i < 16; ++i) wL2[i] = *(const f16x8*)(pW + (8 + i) * 1024);
#pragma unroll
  for (int i = 0; i < 8; ++i)  wL3[i] = *(const f16x8*)(pW + (24 + i) * 1024);

  const uint32_t* keys = (const uint32_t*)((const char*)ws + kKeysOff) + samp * 128;
  const f32x4*    stab = (const f32x4*)((const char*)ws + kStabOff);

  __syncthreads();

  // ---- hoist biases from LDS into registers (read once) ----
  f32x4 b1q[2], w1q[2], b2q[2], b3q;
#pragma unroll
  for (int mt = 0; mt < 2; ++mt) {
    const int nb = w * 32 + mt * 16 + lq * 4;
    b1q[mt] = *(const f32x4*)&bb[nb];
    w1q[mt] = *(const f32x4*)&bb[256 + nb];
    b2q[mt] = *(const f32x4*)&bb[512 + nb];
  }
  b3q = *(const f32x4*)&bb[768 + d0];

  // ---- hoist: pre[nt][mt] = W1[x0 rows]·x0 (step-invariant) ----
  f16x4 pre[4][2];
#pragma unroll
  for (int nt = 0; nt < 4; ++nt) {
    const f16x8 xf0 = *(const f16x8*)(h1f + (0 * 4 + nt) * 1024 + rbs);
    const f16x8 xf1 = *(const f16x8*)(h1f + (1 * 4 + nt) * 1024 + rbs);
#pragma unroll
    for (int mt = 0; mt < 2; ++mt) {
      f32x4 p = {0.f, 0.f, 0.f, 0.f};
      p = MFMA16(wx0[mt][0], xf0, p);
      p = MFMA16(wx0[mt][1], xf1, p);
      f16x4 ph;
#pragma unroll
      for (int q = 0; q < 4; ++q) ph[q] = (_Float16)p[q];
      pre[nt][mt] = ph;
    }
  }
  __syncthreads();   // scratch reads done before L1 overwrites h1f

  // ---- RNG pipeline prologue: etas for step 0 ----
  float etaA[4], etaB[4];
  {
    const uint32_t ka = keys[0], kb0 = keys[1];
#pragma unroll
    for (int q = 0; q < 4; ++q) etaA[q] = bits_to_normal(draw_bits(ka, kb0, giA + q));
#pragma unroll
    for (int q = 0; q < 4; ++q) etaB[q] = bits_to_normal(draw_bits(ka, kb0, giB + q));
  }

  for (int n = 0; n < kSteps; ++n) {
    const f32x4 st = stab[n];
    const float s = st[0], P = st[3];
    const int np = (n + 1 < kSteps) ? n + 1 : n;
    const uint32_t kna = keys[2 * np], knb = keys[2 * np + 1];

    // ========== layer 1: M=32, N=64, K=64 (x only; x0+bias in C-init) =====
#pragma unroll
    for (int nt = 0; nt < 4; ++nt) {
      const f16x8 bf0 = *(const f16x8*)(xAf + (0 * 4 + nt) * 1024 + rbs);
      const f16x8 bf1 = *(const f16x8*)(xAf + (1 * 4 + nt) * 1024 + rbs);
#pragma unroll
      for (int mt = 0; mt < 2; ++mt) {
        const f16x4 ph = pre[nt][mt];
        f32x4 c;
#pragma unroll
        for (int q = 0; q < 4; ++q)
          c[q] = (float)ph[q] + fmaf(s, w1q[mt][q], b1q[mt][q]);
        c = MFMA16(wL1[mt][0], bf0, c);
        c = MFMA16(wL1[mt][1], bf1, c);
        f16x4 o;
#pragma unroll
        for (int q = 0; q < 4; ++q)
          o[q] = (_Float16)fmaxf(c[q], 0.f);
        *(f16x4*)(h1f + (w * 4 + nt) * 1024 + mt * 512 + lo1s) = o;
      }
    }
    __syncthreads();

    // ========== layer 2: M=32, N=64, K=256 (bias in C-init) + next RNG ====
    float enA[4], enB[4];
#pragma unroll
    for (int ntp = 0; ntp < 2; ++ntp) {
      f32x4 c[2][2];
#pragma unroll
      for (int mt = 0; mt < 2; ++mt) {
        c[mt][0] = b2q[mt];
        c[mt][1] = b2q[mt];
      }
#pragma unroll
      for (int half = 0; half < 2; ++half) {
        f16x8 bh[2][4];
#pragma unroll
        for (int ni = 0; ni < 2; ++ni)
#pragma unroll
          for (int k4 = 0; k4 < 4; ++k4)
            bh[ni][k4] = *(const f16x8*)
                (h1f + ((half * 4 + k4) * 4 + ntp * 2 + ni) * 1024 + rbs);
#pragma unroll
        for (int mt = 0; mt < 2; ++mt)
#pragma unroll
          for (int k4 = 0; k4 < 4; ++k4) {
            const f16x8 aW = wL2[mt * 8 + half * 4 + k4];
            c[mt][0] = MFMA16(aW, bh[0][k4], c[mt][0]);
            c[mt][1] = MFMA16(aW, bh[1][k4], c[mt][1]);
          }
      }
      // next-step RNG draws interleave with this region's MFMA/LDS waits
      if (ntp == 0) {
#pragma unroll
        for (int q = 0; q < 4; ++q)
          enA[q] = bits_to_normal(draw_bits(kna, knb, giA + q));
      } else {
#pragma unroll
        for (int q = 0; q < 4; ++q)
          enB[q] = bits_to_normal(draw_bits(kna, knb, giB + q));
      }
#pragma unroll
      for (int mt = 0; mt < 2; ++mt) {
#pragma unroll
        for (int ni = 0; ni < 2; ++ni) {
          f16x4 o;
#pragma unroll
          for (int q = 0; q < 4; ++q)
            o[q] = (_Float16)fmaxf(c[mt][ni][q], 0.f);
          *(f16x4*)(h2f + (w * 4 + ntp * 2 + ni) * 1024 + mt * 512 + lo1s) = o;
        }
      }
    }
    __syncthreads();

    // ========== layer 3 (b3 in C-init) + fused update ==========
#pragma unroll
    for (int ni = 0; ni < 2; ++ni) {
      f32x4 dA = b3q, dB = {0.f, 0.f, 0.f, 0.f};
#pragma unroll
      for (int half = 0; half < 2; ++half) {
        f16x8 bh[4];
#pragma unroll
        for (int k4 = 0; k4 < 4; ++k4)
          bh[k4] = *(const f16x8*)
              (h2f + ((half * 4 + k4) * 4 + ntb + ni) * 1024 + rbs);
        dA = MFMA16(wL3[half * 4 + 0], bh[0], dA);
        dB = MFMA16(wL3[half * 4 + 1], bh[1], dB);
        dA = MFMA16(wL3[half * 4 + 2], bh[2], dA);
        dB = MFMA16(wL3[half * 4 + 3], bh[3], dB);
      }
      f16x4 hx;
#pragma unroll
      for (int q = 0; q < 4; ++q) {
        const float ov  = dA[q] + dB[q];
        const float eta = ni ? etaB[q] : etaA[q];
        // nx = xv + ds*ov + P*(s*ov - xv + x0q) + sqrt(ds)*eta
        const float t1  = fmaf(s, ov, x0q[ni][q] - xv[ni][q]);
        float nx = fmaf(kSqrtDs, eta, xv[ni][q]);
        nx = fmaf(kDs, ov, nx);
        nx = fmaf(P, t1, nx);
        xv[ni][q] = nx;
        hx[q] = (_Float16)nx;
      }
      *(f16x4*)(xAf + (kt3 * 4 + ntb + ni) * 1024 + ln3s) = hx;
    }
    // rotate RNG pipeline
#pragma unroll
    for (int q = 0; q < 4; ++q) { etaA[q] = enA[q]; etaB[q] = enB[q]; }
    __syncthreads();
  }

  // ---- write result (each lane owns its 8 elements) ----
#pragma unroll
  for (int ni = 0; ni < 2; ++ni) {
    const int row = (ntb + ni) * 16 + lm;
    const size_t ob = (size_t)samp * ((size_t)kObs * kDim) +
                      (size_t)(r0 + row) * kDim + d0;
    f32x4 v;
#pragma unroll
    for (int q = 0; q < 4; ++q) v[q] = xv[ni][q];
    *(f32x4*)(out + ob) = v;
  }
}

extern "C" void kernel_launch(void* const* d_in, const int* in_sizes, int n_in,
                              void* d_out, int out_size, void* d_ws, size_t ws_size,
                              hipStream_t stream) {
  const float* X0 = (const float*)d_in[0];
  const float* W1 = (const float*)d_in[1];
  const float* b1 = (const float*)d_in[2];
  const float* W2 = (const float*)d_in[3];
  const float* b2 = (const float*)d_in[4];
  const float* W3 = (const float*)d_in[5];
  const float* b3 = (const float*)d_in[6];
  _Float16* ws = (_Float16*)d_ws;   // 256 KB fragments + 2 KB key/scalar tables

  prep_weights<<<dim3(257), dim3(256), 0, stream>>>(W1, W2, W3, ws);
  sde_mfma<<<dim3(2048), dim3(512), 0, stream>>>(X0, W1, b1, b2, b3, ws,
                                                 (float*)d_out);
}